// Round 1
// baseline (229.723 us; speedup 1.0000x reference)
//
#include <hip/hip_runtime.h>
#include <hip/hip_bf16.h>
#include <math.h>

// Problem constants
#define BATCH 2
#define SEQ   2048
#define DIM   1024
#define HEADS 16
#define DH    64
#define MROWS (BATCH*SEQ)      // 4096
#define NTOT  3072             // q(1024) | k(1024) | v(1024)
#define KDIM  1024

typedef float f32x4 __attribute__((ext_vector_type(4)));
typedef __bf16 bf16x8 __attribute__((ext_vector_type(8)));
typedef __bf16 bf16x4 __attribute__((ext_vector_type(4)));

__device__ __forceinline__ void gload_lds16(const void* g, void* l) {
    // async global->LDS, 16B per lane; LDS dest must be wave-uniform base (+lane*16 implicit)
    __builtin_amdgcn_global_load_lds((__attribute__((address_space(1))) void*)g,
                                     (__attribute__((address_space(3))) void*)l,
                                     16, 0, 0);
}

// ---------------------------------------------------------------- cast x -> bf16
__global__ void cast_x_kernel(const float* __restrict__ x, __bf16* __restrict__ xb) {
    int i = blockIdx.x * 256 + threadIdx.x;       // 4096*256 = 1M float4 = 4M floats exactly
    float4 f = ((const float4*)x)[i];
    bf16x4 o;
    o.x = (__bf16)f.x; o.y = (__bf16)f.y; o.z = (__bf16)f.z; o.w = (__bf16)f.w;
    ((bf16x4*)xb)[i] = o;
}

// ---------------------------------------------- transpose [Wqk|Wv] -> Wt (NTOT,KDIM) bf16
__global__ void transpose_w_kernel(const float* __restrict__ Wqk, const float* __restrict__ Wv,
                                   __bf16* __restrict__ Wt) {
    const int n0 = blockIdx.x * 64;
    const int k0 = blockIdx.y * 64;
    __shared__ float T[64*65];
    const int tid = threadIdx.x;
#pragma unroll
    for (int i = 0; i < 16; ++i) {
        int idx = i*256 + tid;
        int kk = idx >> 6, nn = idx & 63;
        int n = n0 + nn;
        float v = (n < 2048) ? Wqk[(size_t)(k0+kk)*2048 + n]
                             : Wv [(size_t)(k0+kk)*1024 + (n - 2048)];
        T[kk*65 + nn] = v;
    }
    __syncthreads();
#pragma unroll
    for (int i = 0; i < 16; ++i) {
        int idx = i*256 + tid;
        int nn = idx >> 6, kk = idx & 63;
        Wt[(size_t)(n0+nn)*KDIM + k0 + kk] = (__bf16)T[kk*65 + nn];
    }
}

// ---------------------------------------------------------------- combined bias
__global__ void build_bias_kernel(const float* __restrict__ bqk, const float* __restrict__ bv,
                                  float* __restrict__ biasc) {
    int i = blockIdx.x*256 + threadIdx.x;
    if (i < NTOT) biasc[i] = (i < 2048) ? bqk[i] : bv[i-2048];
}

// ---------------------------------------------------------------- GEMM (m97 structure)
// C(4096,3072) = A(4096,1024) * Wt(3072,1024)^T + bias ; all bf16 in, bf16 out, fp32 acc
#define BM 128
#define BN 128
#define BK 32

__global__ __launch_bounds__(256) void gemm_qkv_kernel(const __bf16* __restrict__ A,
                                                       const __bf16* __restrict__ Bt,
                                                       const float* __restrict__ bias,
                                                       __bf16* __restrict__ C) {
    __shared__ alignas(16) __bf16 As[BM*BK];
    __shared__ alignas(16) __bf16 Bs[BN*BK];
    const int tid = threadIdx.x;
    const int wv = tid >> 6, ln = tid & 63;
    const int quad = ln >> 4, lm = ln & 15;
    const int m0 = blockIdx.y * BM, n0 = blockIdx.x * BN;
    const int wm = (wv >> 1) * 64, wn = (wv & 1) * 64;

    f32x4 acc[4][4] = {};

    for (int kt = 0; kt < KDIM/BK; ++kt) {
        const int k0 = kt * BK;
        __syncthreads();          // prev iteration's ds_reads complete before overwrite
#pragma unroll
        for (int i = 0; i < 2; ++i) {
            int c = wv*128 + i*64 + ln;          // chunk id 0..511 (16B chunks)
            int row = c >> 2, kc = (c & 3) * 8;  // 4 chunks per 32-elem row
            gload_lds16(A  + (size_t)(m0 + row)*KDIM + k0 + kc, &As[(wv*128 + i*64)*8]);
            gload_lds16(Bt + (size_t)(n0 + row)*KDIM + k0 + kc, &Bs[(wv*128 + i*64)*8]);
        }
        __syncthreads();          // drains vmcnt(0): LDS tiles ready
        bf16x8 af[4], bfr[4];
#pragma unroll
        for (int mt = 0; mt < 4; ++mt)
            af[mt] = *(const bf16x8*)&As[(wm + mt*16 + lm)*BK + quad*8];
#pragma unroll
        for (int nt = 0; nt < 4; ++nt)
            bfr[nt] = *(const bf16x8*)&Bs[(wn + nt*16 + lm)*BK + quad*8];
#pragma unroll
        for (int mt = 0; mt < 4; ++mt)
#pragma unroll
            for (int nt = 0; nt < 4; ++nt)
                acc[mt][nt] = __builtin_amdgcn_mfma_f32_16x16x32_bf16(af[mt], bfr[nt], acc[mt][nt], 0, 0, 0);
    }
    // epilogue: bias + bf16 store. C/D layout: row = quad*4+r, col = lm  (m89-verified)
#pragma unroll
    for (int mt = 0; mt < 4; ++mt) {
        int rbase = m0 + wm + mt*16 + quad*4;
#pragma unroll
        for (int nt = 0; nt < 4; ++nt) {
            int col = n0 + wn + nt*16 + lm;
            float bs = bias[col];
#pragma unroll
            for (int r = 0; r < 4; ++r)
                C[(size_t)(rbase + r)*NTOT + col] = (__bf16)(acc[mt][nt][r] + bs);
        }
    }
}

// ------------------------------------------- transpose v part of qkv -> vT[bh][dv][s]
__global__ void transpose_v_kernel(const __bf16* __restrict__ qkv, __bf16* __restrict__ vT) {
    const int bh = blockIdx.y;                 // 0..31
    const int b = bh >> 4, h = bh & 15;
    const int kv0 = blockIdx.x * 64;
    __shared__ __bf16 T[64*66];
    const int tid = threadIdx.x;
#pragma unroll
    for (int i = 0; i < 16; ++i) {
        int idx = i*256 + tid;
        int kk = idx >> 6, dd = idx & 63;
        T[kk*66 + dd] = qkv[(size_t)(b*SEQ + kv0 + kk)*NTOT + 2048 + h*64 + dd];
    }
    __syncthreads();
#pragma unroll
    for (int i = 0; i < 16; ++i) {
        int idx = i*256 + tid;
        int dd = idx >> 6, kk = idx & 63;
        vT[((size_t)bh*64 + dd)*SEQ + kv0 + kk] = T[kk*66 + dd];
    }
}

// ---------------------------------------------------------------- flash attention
// grid (32 bh, 16 qtiles), 256 thr = 4 waves; BQ=128, each wave 32 q-rows (2 m-tiles); KV tile 64
#define PSTR 72   // P LDS row stride (elems): 144B rows -> 16B aligned b128 reads

__global__ __launch_bounds__(256) void attn_kernel(const __bf16* __restrict__ qkv,
                                                   const __bf16* __restrict__ vT,
                                                   float* __restrict__ out) {
    const int bh = blockIdx.x;
    const int b = bh >> 4, h = bh & 15;
    const int qt = (int)gridDim.y - 1 - (int)blockIdx.y;   // heavy blocks first
    const int qb = qt * 128;
    const int tid = threadIdx.x, wv = tid >> 6, ln = tid & 63;
    const int quad = ln >> 4, lm = ln & 15;
    const int q0w = qb + wv*32;

    __shared__ alignas(16) __bf16 Ks[64*64];         // [kv][feat]
    __shared__ alignas(16) __bf16 Vs[64*64];         // [dv][kv]  (from vT)
    __shared__ alignas(16) __bf16 Ps[4][32*PSTR];    // per-wave P

    // Q fragments (A-operand layout: A[m=lm][k=quad*8+j]), resident whole kernel
    bf16x8 qf[2][2];
#pragma unroll
    for (int mt = 0; mt < 2; ++mt)
#pragma unroll
        for (int kf = 0; kf < 2; ++kf)
            qf[mt][kf] = *(const bf16x8*)&qkv[(size_t)(b*SEQ + q0w + mt*16 + lm)*NTOT + h*64 + kf*32 + quad*8];

    f32x4 o[2][4] = {};
    float mrow[2][4], lrow[2][4];
#pragma unroll
    for (int mt = 0; mt < 2; ++mt)
#pragma unroll
        for (int r = 0; r < 4; ++r) { mrow[mt][r] = -INFINITY; lrow[mt][r] = 0.f; }

    const size_t kbase = (size_t)b*SEQ*NTOT + 1024 + h*64;
    const size_t vbase = (size_t)bh*64*SEQ;
    const int nsteps = (qb + 128) / 64;

    for (int st = 0; st < nsteps; ++st) {
        const int kv0 = st * 64;
        __syncthreads();
#pragma unroll
        for (int i = 0; i < 2; ++i) {
            int c = wv*128 + i*64 + ln;            // 512 chunks of 16B per tile
            int row = c >> 3, cc = (c & 7) * 8;
            gload_lds16(qkv + kbase + (size_t)(kv0 + row)*NTOT + cc, &Ks[(wv*128 + i*64)*8]);
            gload_lds16(vT + vbase + (size_t)row*SEQ + kv0 + cc,     &Vs[(wv*128 + i*64)*8]);
        }
        __syncthreads();

        if (kv0 <= q0w + 31) {
            // ---- S = Q K^T (C layout)
            f32x4 s[2][4] = {};
            bf16x8 kfrag[4][2];
#pragma unroll
            for (int nt = 0; nt < 4; ++nt)
#pragma unroll
                for (int kf = 0; kf < 2; ++kf)
                    kfrag[nt][kf] = *(const bf16x8*)&Ks[(nt*16 + lm)*64 + kf*32 + quad*8];
#pragma unroll
            for (int mt = 0; mt < 2; ++mt)
#pragma unroll
                for (int nt = 0; nt < 4; ++nt)
#pragma unroll
                    for (int kf = 0; kf < 2; ++kf)
                        s[mt][nt] = __builtin_amdgcn_mfma_f32_16x16x32_bf16(qf[mt][kf], kfrag[nt][kf], s[mt][nt], 0, 0, 0);

            // ---- scale + causal mask (exact -1e9 like reference)
            const bool needmask = (kv0 + 63 > q0w);
#pragma unroll
            for (int mt = 0; mt < 2; ++mt)
#pragma unroll
                for (int nt = 0; nt < 4; ++nt)
#pragma unroll
                    for (int r = 0; r < 4; ++r) {
                        float v = s[mt][nt][r] * 0.125f;
                        if (needmask) {
                            int colg = kv0 + nt*16 + lm;
                            int rowg = q0w + mt*16 + quad*4 + r;
                            if (colg > rowg) v = -1e9f;
                        }
                        s[mt][nt][r] = v;
                    }

            // ---- online softmax per row (row = quad*4+r within m-tile; 16 lanes share a row)
#pragma unroll
            for (int mt = 0; mt < 2; ++mt)
#pragma unroll
                for (int r = 0; r < 4; ++r) {
                    float vmax = fmaxf(fmaxf(s[mt][0][r], s[mt][1][r]), fmaxf(s[mt][2][r], s[mt][3][r]));
                    vmax = fmaxf(vmax, __shfl_xor(vmax, 1));
                    vmax = fmaxf(vmax, __shfl_xor(vmax, 2));
                    vmax = fmaxf(vmax, __shfl_xor(vmax, 4));
                    vmax = fmaxf(vmax, __shfl_xor(vmax, 8));
                    float mnew  = fmaxf(mrow[mt][r], vmax);
                    float alpha = __expf(mrow[mt][r] - mnew);
                    mrow[mt][r] = mnew;
                    float rsum = 0.f;
#pragma unroll
                    for (int nt = 0; nt < 4; ++nt) {
                        float p = __expf(s[mt][nt][r] - mnew);
                        __bf16 pb = (__bf16)p;
                        Ps[wv][(mt*16 + quad*4 + r)*PSTR + nt*16 + lm] = pb;
                        rsum += (float)pb;            // sum the values PV actually uses
                    }
                    rsum += __shfl_xor(rsum, 1);
                    rsum += __shfl_xor(rsum, 2);
                    rsum += __shfl_xor(rsum, 4);
                    rsum += __shfl_xor(rsum, 8);
                    lrow[mt][r] = alpha * lrow[mt][r] + rsum;
#pragma unroll
                    for (int nb = 0; nb < 4; ++nb) o[mt][nb][r] *= alpha;
                }

            // ---- O += P V  (P via per-wave LDS: wave-local RAW, no barrier needed)
            bf16x8 vfrag[4][2];
#pragma unroll
            for (int nb = 0; nb < 4; ++nb)
#pragma unroll
                for (int kf = 0; kf < 2; ++kf)
                    vfrag[nb][kf] = *(const bf16x8*)&Vs[(nb*16 + lm)*64 + kf*32 + quad*8];
#pragma unroll
            for (int mt = 0; mt < 2; ++mt) {
                bf16x8 pf0 = *(const bf16x8*)&Ps[wv][(mt*16 + lm)*PSTR + quad*8];
                bf16x8 pf1 = *(const bf16x8*)&Ps[wv][(mt*16 + lm)*PSTR + 32 + quad*8];
#pragma unroll
                for (int nb = 0; nb < 4; ++nb) {
                    o[mt][nb] = __builtin_amdgcn_mfma_f32_16x16x32_bf16(pf0, vfrag[nb][0], o[mt][nb], 0, 0, 0);
                    o[mt][nb] = __builtin_amdgcn_mfma_f32_16x16x32_bf16(pf1, vfrag[nb][1], o[mt][nb], 0, 0, 0);
                }
            }
        }
    }

    // ---- epilogue: out[b][s][h*64+dv] = O/l  (fp32)
#pragma unroll
    for (int mt = 0; mt < 2; ++mt)
#pragma unroll
        for (int nb = 0; nb < 4; ++nb)
#pragma unroll
            for (int r = 0; r < 4; ++r) {
                int rowg = q0w + mt*16 + quad*4 + r;
                out[(size_t)(b*SEQ + rowg)*DIM + h*64 + nb*16 + lm] = o[mt][nb][r] / lrow[mt][r];
            }
}

// ---------------------------------------------------------------- launcher
extern "C" void kernel_launch(void* const* d_in, const int* in_sizes, int n_in,
                              void* d_out, int out_size, void* d_ws, size_t ws_size,
                              hipStream_t stream) {
    const float* x   = (const float*)d_in[0];
    const float* Wqk = (const float*)d_in[1];
    const float* bqk = (const float*)d_in[2];
    const float* Wv  = (const float*)d_in[3];
    const float* bv  = (const float*)d_in[4];
    float* out = (float*)d_out;

    char* ws = (char*)d_ws;
    const size_t SZ_XB  = (size_t)MROWS*KDIM*2;   // 8 MB
    const size_t SZ_WT  = (size_t)NTOT*KDIM*2;    // 6 MB
    const size_t SZ_QKV = (size_t)MROWS*NTOT*2;   // 24 MB
    const size_t SZ_VT  = (size_t)32*64*SEQ*2;    // 8 MB
    __bf16* xb    = (__bf16*)(ws);
    __bf16* Wt    = (__bf16*)(ws + SZ_XB);
    __bf16* qkv   = (__bf16*)(ws + SZ_XB + SZ_WT);
    __bf16* vT    = (__bf16*)(ws + SZ_XB + SZ_WT + SZ_QKV);
    float*  biasc = (float* )(ws + SZ_XB + SZ_WT + SZ_QKV + SZ_VT);

    cast_x_kernel     <<<4096, 256, 0, stream>>>(x, xb);
    transpose_w_kernel<<<dim3(48, 16), 256, 0, stream>>>(Wqk, Wv, Wt);
    build_bias_kernel <<<12, 256, 0, stream>>>(bqk, bv, biasc);
    gemm_qkv_kernel   <<<dim3(NTOT/BN, MROWS/BM), 256, 0, stream>>>(xb, Wt, biasc, qkv);
    transpose_v_kernel<<<dim3(32, 32), 256, 0, stream>>>(qkv, vT);
    attn_kernel       <<<dim3(32, 16), 256, 0, stream>>>(qkv, vT, out);
}

// Round 2
// 208.316 us; speedup vs baseline: 1.1028x; 1.1028x over previous
//
#include <hip/hip_runtime.h>
#include <hip/hip_bf16.h>
#include <math.h>

// Problem constants
#define BATCH 2
#define SEQ   2048
#define DIM   1024
#define HEADS 16
#define DH    64
#define MROWS (BATCH*SEQ)      // 4096
#define NTOT  3072             // q(1024) | k(1024) | v(1024)
#define KDIM  1024

typedef float f32x4 __attribute__((ext_vector_type(4)));
typedef __bf16 bf16x8 __attribute__((ext_vector_type(8)));
typedef __bf16 bf16x4 __attribute__((ext_vector_type(4)));

__device__ __forceinline__ void gload_lds16(const void* g, void* l) {
    // async global->LDS, 16B per lane; LDS dest must be wave-uniform base (+lane*16 implicit)
    __builtin_amdgcn_global_load_lds((__attribute__((address_space(1))) void*)g,
                                     (__attribute__((address_space(3))) void*)l,
                                     16, 0, 0);
}

// ---------------------------------------------------------------- cast x -> bf16
__global__ void cast_x_kernel(const float* __restrict__ x, __bf16* __restrict__ xb) {
    int i = blockIdx.x * 256 + threadIdx.x;       // 4096*256 = 1M float4 = 4M floats exactly
    float4 f = ((const float4*)x)[i];
    bf16x4 o;
    o.x = (__bf16)f.x; o.y = (__bf16)f.y; o.z = (__bf16)f.z; o.w = (__bf16)f.w;
    ((bf16x4*)xb)[i] = o;
}

// ---------------------------------------------- transpose [Wqk|Wv] -> Wt (NTOT,KDIM) bf16
__global__ void transpose_w_kernel(const float* __restrict__ Wqk, const float* __restrict__ Wv,
                                   __bf16* __restrict__ Wt) {
    const int n0 = blockIdx.x * 64;
    const int k0 = blockIdx.y * 64;
    __shared__ float T[64*65];
    const int tid = threadIdx.x;
#pragma unroll
    for (int i = 0; i < 16; ++i) {
        int idx = i*256 + tid;
        int kk = idx >> 6, nn = idx & 63;
        int n = n0 + nn;
        float v = (n < 2048) ? Wqk[(size_t)(k0+kk)*2048 + n]
                             : Wv [(size_t)(k0+kk)*1024 + (n - 2048)];
        T[kk*65 + nn] = v;
    }
    __syncthreads();
#pragma unroll
    for (int i = 0; i < 16; ++i) {
        int idx = i*256 + tid;
        int nn = idx >> 6, kk = idx & 63;
        Wt[(size_t)(n0+nn)*KDIM + k0 + kk] = (__bf16)T[kk*65 + nn];
    }
}

// ---------------------------------------------------------------- combined bias
__global__ void build_bias_kernel(const float* __restrict__ bqk, const float* __restrict__ bv,
                                  float* __restrict__ biasc) {
    int i = blockIdx.x*256 + threadIdx.x;
    if (i < NTOT) biasc[i] = (i < 2048) ? bqk[i] : bv[i-2048];
}

// ---------------------------------------------------------------- GEMM (m97 structure)
// C(4096,3072) = A(4096,1024) * Wt(3072,1024)^T + bias ; all bf16 in, bf16 out, fp32 acc
#define BM 128
#define BN 128
#define BK 32

__global__ __launch_bounds__(256) void gemm_qkv_kernel(const __bf16* __restrict__ A,
                                                       const __bf16* __restrict__ Bt,
                                                       const float* __restrict__ bias,
                                                       __bf16* __restrict__ C) {
    __shared__ alignas(16) __bf16 As[BM*BK];
    __shared__ alignas(16) __bf16 Bs[BN*BK];
    const int tid = threadIdx.x;
    const int wv = tid >> 6, ln = tid & 63;
    const int quad = ln >> 4, lm = ln & 15;
    const int m0 = blockIdx.y * BM, n0 = blockIdx.x * BN;
    const int wm = (wv >> 1) * 64, wn = (wv & 1) * 64;

    f32x4 acc[4][4] = {};

    for (int kt = 0; kt < KDIM/BK; ++kt) {
        const int k0 = kt * BK;
        __syncthreads();          // prev iteration's ds_reads complete before overwrite
#pragma unroll
        for (int i = 0; i < 2; ++i) {
            int c = wv*128 + i*64 + ln;          // chunk id 0..511 (16B chunks)
            int row = c >> 2, kc = (c & 3) * 8;  // 4 chunks per 32-elem row
            gload_lds16(A  + (size_t)(m0 + row)*KDIM + k0 + kc, &As[(wv*128 + i*64)*8]);
            gload_lds16(Bt + (size_t)(n0 + row)*KDIM + k0 + kc, &Bs[(wv*128 + i*64)*8]);
        }
        __syncthreads();          // drains vmcnt(0): LDS tiles ready
        bf16x8 af[4], bfr[4];
#pragma unroll
        for (int mt = 0; mt < 4; ++mt)
            af[mt] = *(const bf16x8*)&As[(wm + mt*16 + lm)*BK + quad*8];
#pragma unroll
        for (int nt = 0; nt < 4; ++nt)
            bfr[nt] = *(const bf16x8*)&Bs[(wn + nt*16 + lm)*BK + quad*8];
#pragma unroll
        for (int mt = 0; mt < 4; ++mt)
#pragma unroll
            for (int nt = 0; nt < 4; ++nt)
                acc[mt][nt] = __builtin_amdgcn_mfma_f32_16x16x32_bf16(af[mt], bfr[nt], acc[mt][nt], 0, 0, 0);
    }
    // epilogue: bias + bf16 store. C/D layout: row = quad*4+r, col = lm  (m89-verified)
#pragma unroll
    for (int mt = 0; mt < 4; ++mt) {
        int rbase = m0 + wm + mt*16 + quad*4;
#pragma unroll
        for (int nt = 0; nt < 4; ++nt) {
            int col = n0 + wn + nt*16 + lm;
            float bs = bias[col];
#pragma unroll
            for (int r = 0; r < 4; ++r)
                C[(size_t)(rbase + r)*NTOT + col] = (__bf16)(acc[mt][nt][r] + bs);
        }
    }
}

// ------------------------------------------- transpose v part of qkv -> vT[bh][dv][s]
__global__ void transpose_v_kernel(const __bf16* __restrict__ qkv, __bf16* __restrict__ vT) {
    const int bh = blockIdx.y;                 // 0..31
    const int b = bh >> 4, h = bh & 15;
    const int kv0 = blockIdx.x * 64;
    __shared__ __bf16 T[64*66];
    const int tid = threadIdx.x;
#pragma unroll
    for (int i = 0; i < 16; ++i) {
        int idx = i*256 + tid;
        int kk = idx >> 6, dd = idx & 63;
        T[kk*66 + dd] = qkv[(size_t)(b*SEQ + kv0 + kk)*NTOT + 2048 + h*64 + dd];
    }
    __syncthreads();
#pragma unroll
    for (int i = 0; i < 16; ++i) {
        int idx = i*256 + tid;
        int dd = idx >> 6, kk = idx & 63;
        vT[((size_t)bh*64 + dd)*SEQ + kv0 + kk] = T[kk*66 + dd];
    }
}

// ---------------------------------------------------------------- flash attention v2
// grid (32 bh, 32 qtiles heavy-first), 256 thr = 4 waves; BQ=64 (16 q-rows/wave); KV tile 64
// 4 blocks/CU co-resident (LDS 25.6KB, __launch_bounds__(256,4) caps VGPR<=128)
#define PSTR 72   // P LDS row stride (elems): 144B rows -> 16B aligned b128 reads

__global__ __launch_bounds__(256, 4) void attn_kernel(const __bf16* __restrict__ qkv,
                                                      const __bf16* __restrict__ vT,
                                                      float* __restrict__ out) {
    const int bh = blockIdx.x;
    const int b = bh >> 4, h = bh & 15;
    const int qt = 31 - (int)blockIdx.y;            // heavy blocks dispatched first
    const int qb = qt * 64;
    const int tid = threadIdx.x, wv = tid >> 6, ln = tid & 63;
    const int quad = ln >> 4, lm = ln & 15;
    const int q0w = qb + wv*16;                     // this wave's 16 q-rows

    __shared__ alignas(16) __bf16 Ks[64*64];        // [kv][feat]
    __shared__ alignas(16) __bf16 Vs[64*64];        // [dv][kv]  (from vT)
    __shared__ alignas(16) __bf16 Ps[4][16*PSTR];   // per-wave P

    // Q fragments (A-layout: A[m=lm][k=quad*8+j]), pre-scaled by 1/8 (exact pow2)
    bf16x8 qf[2];
#pragma unroll
    for (int kf = 0; kf < 2; ++kf) {
        bf16x8 t = *(const bf16x8*)&qkv[(size_t)(b*SEQ + q0w + lm)*NTOT + h*64 + kf*32 + quad*8];
#pragma unroll
        for (int j = 0; j < 8; ++j) t[j] = (__bf16)((float)t[j] * 0.125f);
        qf[kf] = t;
    }

    f32x4 o[4] = {};
    float mrow[4], lrow[4];
#pragma unroll
    for (int r = 0; r < 4; ++r) { mrow[r] = -INFINITY; lrow[r] = 0.f; }

    const size_t kbase = (size_t)b*SEQ*NTOT + 1024 + h*64;
    const size_t vbase = (size_t)bh*64*SEQ;
    const int nsteps = qt + 1;

    for (int st = 0; st < nsteps; ++st) {
        const int kv0 = st * 64;
        __syncthreads();
#pragma unroll
        for (int i = 0; i < 2; ++i) {
            int c = wv*128 + i*64 + ln;             // 512 chunks of 16B per tile
            int row = c >> 3, cc = (c & 7) * 8;
            gload_lds16(qkv + kbase + (size_t)(kv0 + row)*NTOT + cc, &Ks[(wv*128 + i*64)*8]);
            gload_lds16(vT + vbase + (size_t)row*SEQ + kv0 + cc,     &Vs[(wv*128 + i*64)*8]);
        }
        __syncthreads();

        // ---- S = Q K^T (C layout: row=quad*4+r, col=lm within each 16-col tile)
        f32x4 s[4] = {};
        bf16x8 kfrag[4][2];
#pragma unroll
        for (int nt = 0; nt < 4; ++nt)
#pragma unroll
            for (int kf = 0; kf < 2; ++kf)
                kfrag[nt][kf] = *(const bf16x8*)&Ks[(nt*16 + lm)*64 + kf*32 + quad*8];
#pragma unroll
        for (int nt = 0; nt < 4; ++nt)
#pragma unroll
            for (int kf = 0; kf < 2; ++kf)
                s[nt] = __builtin_amdgcn_mfma_f32_16x16x32_bf16(qf[kf], kfrag[nt][kf], s[nt], 0, 0, 0);

        // ---- causal mask (S already carries the 1/8 scale via Q; -1e9 matches ref)
        if (kv0 + 63 > q0w) {                       // true on exactly the diagonal step
#pragma unroll
            for (int nt = 0; nt < 4; ++nt)
#pragma unroll
                for (int r = 0; r < 4; ++r) {
                    int colg = kv0 + nt*16 + lm;
                    int rowg = q0w + quad*4 + r;
                    if (colg > rowg) s[nt][r] = -1e9f;
                }
        }

        // ---- online softmax per row (row = quad*4+r; 16 lanes share a row)
#pragma unroll
        for (int r = 0; r < 4; ++r) {
            float vmax = fmaxf(fmaxf(s[0][r], s[1][r]), fmaxf(s[2][r], s[3][r]));
            vmax = fmaxf(vmax, __shfl_xor(vmax, 1));
            vmax = fmaxf(vmax, __shfl_xor(vmax, 2));
            vmax = fmaxf(vmax, __shfl_xor(vmax, 4));
            vmax = fmaxf(vmax, __shfl_xor(vmax, 8));
            float mnew  = fmaxf(mrow[r], vmax);
            float alpha = __expf(mrow[r] - mnew);
            mrow[r] = mnew;
            float rsum = 0.f;
#pragma unroll
            for (int nt = 0; nt < 4; ++nt) {
                float p = __expf(s[nt][r] - mnew);
                __bf16 pb = (__bf16)p;
                Ps[wv][(quad*4 + r)*PSTR + nt*16 + lm] = pb;
                rsum += (float)pb;                  // sum the values PV actually uses
            }
            rsum += __shfl_xor(rsum, 1);
            rsum += __shfl_xor(rsum, 2);
            rsum += __shfl_xor(rsum, 4);
            rsum += __shfl_xor(rsum, 8);
            lrow[r] = alpha * lrow[r] + rsum;
#pragma unroll
            for (int nb = 0; nb < 4; ++nb) o[nb][r] *= alpha;
        }

        // ---- O += P V  (P via per-wave LDS: wave-local RAW, no barrier needed)
        bf16x8 vfrag[4][2];
#pragma unroll
        for (int nb = 0; nb < 4; ++nb)
#pragma unroll
            for (int kf = 0; kf < 2; ++kf)
                vfrag[nb][kf] = *(const bf16x8*)&Vs[(nb*16 + lm)*64 + kf*32 + quad*8];
        bf16x8 pf0 = *(const bf16x8*)&Ps[wv][lm*PSTR + quad*8];
        bf16x8 pf1 = *(const bf16x8*)&Ps[wv][lm*PSTR + 32 + quad*8];
#pragma unroll
        for (int nb = 0; nb < 4; ++nb) {
            o[nb] = __builtin_amdgcn_mfma_f32_16x16x32_bf16(pf0, vfrag[nb][0], o[nb], 0, 0, 0);
            o[nb] = __builtin_amdgcn_mfma_f32_16x16x32_bf16(pf1, vfrag[nb][1], o[nb], 0, 0, 0);
        }
    }

    // ---- epilogue: out[b][s][h*64+dv] = O/l  (fp32)
#pragma unroll
    for (int nb = 0; nb < 4; ++nb)
#pragma unroll
        for (int r = 0; r < 4; ++r) {
            int rowg = q0w + quad*4 + r;
            out[(size_t)(b*SEQ + rowg)*DIM + h*64 + nb*16 + lm] = o[nb][r] / lrow[r];
        }
}

// ---------------------------------------------------------------- launcher
extern "C" void kernel_launch(void* const* d_in, const int* in_sizes, int n_in,
                              void* d_out, int out_size, void* d_ws, size_t ws_size,
                              hipStream_t stream) {
    const float* x   = (const float*)d_in[0];
    const float* Wqk = (const float*)d_in[1];
    const float* bqk = (const float*)d_in[2];
    const float* Wv  = (const float*)d_in[3];
    const float* bv  = (const float*)d_in[4];
    float* out = (float*)d_out;

    char* ws = (char*)d_ws;
    const size_t SZ_XB  = (size_t)MROWS*KDIM*2;   // 8 MB
    const size_t SZ_WT  = (size_t)NTOT*KDIM*2;    // 6 MB
    const size_t SZ_QKV = (size_t)MROWS*NTOT*2;   // 24 MB
    const size_t SZ_VT  = (size_t)32*64*SEQ*2;    // 8 MB
    __bf16* xb    = (__bf16*)(ws);
    __bf16* Wt    = (__bf16*)(ws + SZ_XB);
    __bf16* qkv   = (__bf16*)(ws + SZ_XB + SZ_WT);
    __bf16* vT    = (__bf16*)(ws + SZ_XB + SZ_WT + SZ_QKV);
    float*  biasc = (float* )(ws + SZ_XB + SZ_WT + SZ_QKV + SZ_VT);

    cast_x_kernel     <<<4096, 256, 0, stream>>>(x, xb);
    transpose_w_kernel<<<dim3(48, 16), 256, 0, stream>>>(Wqk, Wv, Wt);
    build_bias_kernel <<<12, 256, 0, stream>>>(bqk, bv, biasc);
    gemm_qkv_kernel   <<<dim3(NTOT/BN, MROWS/BM), 256, 0, stream>>>(xb, Wt, biasc, qkv);
    transpose_v_kernel<<<dim3(32, 32), 256, 0, stream>>>(qkv, vT);
    attn_kernel       <<<dim3(32, 32), 256, 0, stream>>>(qkv, vT, out);
}

// Round 3
// 186.171 us; speedup vs baseline: 1.2339x; 1.1190x over previous
//
#include <hip/hip_runtime.h>
#include <hip/hip_bf16.h>
#include <math.h>

// Problem constants
#define BATCH 2
#define SEQ   2048
#define DIM   1024
#define HEADS 16
#define DH    64
#define MROWS (BATCH*SEQ)      // 4096
#define NTOT  3072             // q(1024) | k(1024) | v(1024)
#define KDIM  1024

typedef float f32x4 __attribute__((ext_vector_type(4)));
typedef __bf16 bf16x8 __attribute__((ext_vector_type(8)));
typedef __bf16 bf16x4 __attribute__((ext_vector_type(4)));

__device__ __forceinline__ void gload_lds16(const void* g, void* l) {
    // async global->LDS, 16B per lane; LDS dest must be wave-uniform base (+lane*16 implicit)
    __builtin_amdgcn_global_load_lds((__attribute__((address_space(1))) void*)g,
                                     (__attribute__((address_space(3))) void*)l,
                                     16, 0, 0);
}

// ---------------------------------------------------------------- cast x -> bf16
__global__ void cast_x_kernel(const float* __restrict__ x, __bf16* __restrict__ xb) {
    int i = blockIdx.x * 256 + threadIdx.x;       // 4096*256 = 1M float4 = 4M floats exactly
    float4 f = ((const float4*)x)[i];
    bf16x4 o;
    o.x = (__bf16)f.x; o.y = (__bf16)f.y; o.z = (__bf16)f.z; o.w = (__bf16)f.w;
    ((bf16x4*)xb)[i] = o;
}

// ---------------------------------------------- transpose [Wqk|Wv] -> Wt (NTOT,KDIM) bf16
__global__ void transpose_w_kernel(const float* __restrict__ Wqk, const float* __restrict__ Wv,
                                   __bf16* __restrict__ Wt) {
    const int n0 = blockIdx.x * 64;
    const int k0 = blockIdx.y * 64;
    __shared__ float T[64*65];
    const int tid = threadIdx.x;
#pragma unroll
    for (int i = 0; i < 16; ++i) {
        int idx = i*256 + tid;
        int kk = idx >> 6, nn = idx & 63;
        int n = n0 + nn;
        float v = (n < 2048) ? Wqk[(size_t)(k0+kk)*2048 + n]
                             : Wv [(size_t)(k0+kk)*1024 + (n - 2048)];
        T[kk*65 + nn] = v;
    }
    __syncthreads();
#pragma unroll
    for (int i = 0; i < 16; ++i) {
        int idx = i*256 + tid;
        int nn = idx >> 6, kk = idx & 63;
        Wt[(size_t)(n0+nn)*KDIM + k0 + kk] = (__bf16)T[kk*65 + nn];
    }
}

// ---------------------------------------------------------------- combined bias
__global__ void build_bias_kernel(const float* __restrict__ bqk, const float* __restrict__ bv,
                                  float* __restrict__ biasc) {
    int i = blockIdx.x*256 + threadIdx.x;
    if (i < NTOT) biasc[i] = (i < 2048) ? bqk[i] : bv[i-2048];
}

// ---------------------------------------------------------------- GEMM (m97 structure)
// C(4096,3072) = A(4096,1024) * Wt(3072,1024)^T + bias ; all bf16 in, bf16 out, fp32 acc
#define BM 128
#define BN 128
#define BK 32

__global__ __launch_bounds__(256) void gemm_qkv_kernel(const __bf16* __restrict__ A,
                                                       const __bf16* __restrict__ Bt,
                                                       const float* __restrict__ bias,
                                                       __bf16* __restrict__ C) {
    __shared__ alignas(16) __bf16 As[BM*BK];
    __shared__ alignas(16) __bf16 Bs[BN*BK];
    const int tid = threadIdx.x;
    const int wv = tid >> 6, ln = tid & 63;
    const int quad = ln >> 4, lm = ln & 15;
    const int m0 = blockIdx.y * BM, n0 = blockIdx.x * BN;
    const int wm = (wv >> 1) * 64, wn = (wv & 1) * 64;

    f32x4 acc[4][4] = {};

    for (int kt = 0; kt < KDIM/BK; ++kt) {
        const int k0 = kt * BK;
        __syncthreads();          // prev iteration's ds_reads complete before overwrite
#pragma unroll
        for (int i = 0; i < 2; ++i) {
            int c = wv*128 + i*64 + ln;          // chunk id 0..511 (16B chunks)
            int row = c >> 2, kc = (c & 3) * 8;  // 4 chunks per 32-elem row
            gload_lds16(A  + (size_t)(m0 + row)*KDIM + k0 + kc, &As[(wv*128 + i*64)*8]);
            gload_lds16(Bt + (size_t)(n0 + row)*KDIM + k0 + kc, &Bs[(wv*128 + i*64)*8]);
        }
        __syncthreads();          // drains vmcnt(0): LDS tiles ready
        bf16x8 af[4], bfr[4];
#pragma unroll
        for (int mt = 0; mt < 4; ++mt)
            af[mt] = *(const bf16x8*)&As[(wm + mt*16 + lm)*BK + quad*8];
#pragma unroll
        for (int nt = 0; nt < 4; ++nt)
            bfr[nt] = *(const bf16x8*)&Bs[(wn + nt*16 + lm)*BK + quad*8];
#pragma unroll
        for (int mt = 0; mt < 4; ++mt)
#pragma unroll
            for (int nt = 0; nt < 4; ++nt)
                acc[mt][nt] = __builtin_amdgcn_mfma_f32_16x16x32_bf16(af[mt], bfr[nt], acc[mt][nt], 0, 0, 0);
    }
    // epilogue: bias + bf16 store. C/D layout: row = quad*4+r, col = lm  (m89-verified)
#pragma unroll
    for (int mt = 0; mt < 4; ++mt) {
        int rbase = m0 + wm + mt*16 + quad*4;
#pragma unroll
        for (int nt = 0; nt < 4; ++nt) {
            int col = n0 + wn + nt*16 + lm;
            float bs = bias[col];
#pragma unroll
            for (int r = 0; r < 4; ++r)
                C[(size_t)(rbase + r)*NTOT + col] = (__bf16)(acc[mt][nt][r] + bs);
        }
    }
}

// ------------------------------------------- transpose v part of qkv -> vT[bh][dv][s]
__global__ void transpose_v_kernel(const __bf16* __restrict__ qkv, __bf16* __restrict__ vT) {
    const int bh = blockIdx.y;                 // 0..31
    const int b = bh >> 4, h = bh & 15;
    const int kv0 = blockIdx.x * 64;
    __shared__ __bf16 T[64*66];
    const int tid = threadIdx.x;
#pragma unroll
    for (int i = 0; i < 16; ++i) {
        int idx = i*256 + tid;
        int kk = idx >> 6, dd = idx & 63;
        T[kk*66 + dd] = qkv[(size_t)(b*SEQ + kv0 + kk)*NTOT + 2048 + h*64 + dd];
    }
    __syncthreads();
#pragma unroll
    for (int i = 0; i < 16; ++i) {
        int idx = i*256 + tid;
        int dd = idx >> 6, kk = idx & 63;
        vT[((size_t)bh*64 + dd)*SEQ + kv0 + kk] = T[kk*66 + dd];
    }
}

// ---------------------------------------------------------------- flash attention v3
// Transposed-S formulation: S^T = K Q^T, O^T = V^T P^T.
//   S^T C-layout: lane(quad,lm) holds (kv = nt*16+quad*4+r, q = lm) -> per-lane scalar m/l,
//   2-shfl reductions, vectorized P stores (ds_write_b64), float4 output stores.
// grid (32 bh, 32 qtiles heavy-first), 256 thr = 4 waves; BQ=64 (16 q-rows/wave); KV tile 64.
// LDS 25.2 KB -> 6 blocks/CU via __launch_bounds__(256,6).
#define PSTR 72   // P^T LDS row stride (elems): [q=16][kv=64+pad], 144B rows

__global__ __launch_bounds__(256, 6) void attn_kernel(const __bf16* __restrict__ qkv,
                                                      const __bf16* __restrict__ vT,
                                                      float* __restrict__ out) {
    const int bh = blockIdx.x;
    const int b = bh >> 4, h = bh & 15;
    const int qt = 31 - (int)blockIdx.y;            // heavy blocks dispatched first
    const int qb = qt * 64;
    const int tid = threadIdx.x, wv = tid >> 6, ln = tid & 63;
    const int quad = ln >> 4, lm = ln & 15;
    const int q0w = qb + wv*16;                     // this wave's 16 q-rows
    const int qg = q0w + lm;                        // this lane's q row

    __shared__ alignas(16) __bf16 Ks[64*64];        // [kv][feat]
    __shared__ alignas(16) __bf16 Vs[64*64];        // [dv][kv]  (from vT)
    __shared__ alignas(16) __bf16 Ps[4][16*PSTR];   // per-wave P^T as [q][kv]

    // Q fragments (B-operand: B[n=lm][k=quad*8+j]), pre-scaled by 1/8 (exact pow2)
    bf16x8 qf[2];
#pragma unroll
    for (int kf = 0; kf < 2; ++kf) {
        bf16x8 t = *(const bf16x8*)&qkv[(size_t)(b*SEQ + q0w + lm)*NTOT + h*64 + kf*32 + quad*8];
#pragma unroll
        for (int j = 0; j < 8; ++j) t[j] = (__bf16)((float)t[j] * 0.125f);
        qf[kf] = t;
    }

    f32x4 o[4] = {};                                // O^T: (dv = nb*16+quad*4+r, q = lm)
    float mrow = -INFINITY, lrow = 0.f;             // per-lane scalars (q = lm)

    const size_t kbase = (size_t)b*SEQ*NTOT + 1024 + h*64;
    const size_t vbase = (size_t)bh*64*SEQ;
    const int nsteps = qt + 1;                      // kv0 max = qb <= q0w : all waves compute all steps

    for (int st = 0; st < nsteps; ++st) {
        const int kv0 = st * 64;
        __syncthreads();
#pragma unroll
        for (int i = 0; i < 2; ++i) {
            int c = wv*128 + i*64 + ln;             // 512 chunks of 16B per tile
            int row = c >> 3, cc = (c & 7) * 8;
            gload_lds16(qkv + kbase + (size_t)(kv0 + row)*NTOT + cc, &Ks[(wv*128 + i*64)*8]);
            gload_lds16(vT + vbase + (size_t)row*SEQ + kv0 + cc,     &Vs[(wv*128 + i*64)*8]);
        }
        __syncthreads();

        // ---- S^T = K Q^T : tile nt holds kv rows [nt*16, nt*16+16)
        f32x4 s[4] = {};
        bf16x8 kfrag[4][2];
#pragma unroll
        for (int nt = 0; nt < 4; ++nt)
#pragma unroll
            for (int kf = 0; kf < 2; ++kf)
                kfrag[nt][kf] = *(const bf16x8*)&Ks[(nt*16 + lm)*64 + kf*32 + quad*8];
#pragma unroll
        for (int nt = 0; nt < 4; ++nt)
#pragma unroll
            for (int kf = 0; kf < 2; ++kf)
                s[nt] = __builtin_amdgcn_mfma_f32_16x16x32_bf16(kfrag[nt][kf], qf[kf], s[nt], 0, 0, 0);

        // ---- causal mask (only the diagonal step needs it; -1e9 matches ref)
        if (kv0 + 63 > q0w) {
#pragma unroll
            for (int nt = 0; nt < 4; ++nt)
#pragma unroll
                for (int r = 0; r < 4; ++r) {
                    int kvg = kv0 + nt*16 + quad*4 + r;
                    if (kvg > qg) s[nt][r] = -1e9f;
                }
        }

        // ---- online softmax: all 16 lane values share q=lm -> scalar m/l
        float vm0 = fmaxf(fmaxf(s[0][0], s[0][1]), fmaxf(s[0][2], s[0][3]));
        float vm1 = fmaxf(fmaxf(s[1][0], s[1][1]), fmaxf(s[1][2], s[1][3]));
        float vm2 = fmaxf(fmaxf(s[2][0], s[2][1]), fmaxf(s[2][2], s[2][3]));
        float vm3 = fmaxf(fmaxf(s[3][0], s[3][1]), fmaxf(s[3][2], s[3][3]));
        float vmax = fmaxf(fmaxf(vm0, vm1), fmaxf(vm2, vm3));
        vmax = fmaxf(vmax, __shfl_xor(vmax, 16));
        vmax = fmaxf(vmax, __shfl_xor(vmax, 32));
        float mnew  = fmaxf(mrow, vmax);
        float alpha = __expf(mrow - mnew);
        mrow = mnew;

        float rsum = 0.f;
#pragma unroll
        for (int nt = 0; nt < 4; ++nt) {
            bf16x4 pb;
#pragma unroll
            for (int r = 0; r < 4; ++r) {
                float p = __expf(s[nt][r] - mnew);
                __bf16 x = (__bf16)p;
                pb[r] = x;
                rsum += (float)x;                   // sum the values PV actually uses
            }
            *(bf16x4*)&Ps[wv][lm*PSTR + nt*16 + quad*4] = pb;   // 8B vectorized store
        }
        rsum += __shfl_xor(rsum, 16);
        rsum += __shfl_xor(rsum, 32);
        lrow = alpha * lrow + rsum;
#pragma unroll
        for (int nb = 0; nb < 4; ++nb)
#pragma unroll
            for (int r = 0; r < 4; ++r) o[nb][r] *= alpha;

        // ---- O^T += V^T P^T  (A = V^T frag, B = P^T frag; wave-local LDS RAW)
        bf16x8 vfrag[4][2];
#pragma unroll
        for (int nb = 0; nb < 4; ++nb)
#pragma unroll
            for (int kf = 0; kf < 2; ++kf)
                vfrag[nb][kf] = *(const bf16x8*)&Vs[(nb*16 + lm)*64 + kf*32 + quad*8];
        bf16x8 pf0 = *(const bf16x8*)&Ps[wv][lm*PSTR + quad*8];
        bf16x8 pf1 = *(const bf16x8*)&Ps[wv][lm*PSTR + 32 + quad*8];
#pragma unroll
        for (int nb = 0; nb < 4; ++nb) {
            o[nb] = __builtin_amdgcn_mfma_f32_16x16x32_bf16(vfrag[nb][0], pf0, o[nb], 0, 0, 0);
            o[nb] = __builtin_amdgcn_mfma_f32_16x16x32_bf16(vfrag[nb][1], pf1, o[nb], 0, 0, 0);
        }
    }

    // ---- epilogue: out[b][q][h*64+dv] = O^T(dv,q)/l ; 4 contiguous dv per lane -> float4
    const float invl = 1.0f / lrow;
    float* orow = out + (size_t)(b*SEQ + q0w + lm)*DIM + h*64;
#pragma unroll
    for (int nb = 0; nb < 4; ++nb) {
        float4 vres;
        vres.x = o[nb][0] * invl;
        vres.y = o[nb][1] * invl;
        vres.z = o[nb][2] * invl;
        vres.w = o[nb][3] * invl;
        *(float4*)&orow[nb*16 + quad*4] = vres;
    }
}

// ---------------------------------------------------------------- launcher
extern "C" void kernel_launch(void* const* d_in, const int* in_sizes, int n_in,
                              void* d_out, int out_size, void* d_ws, size_t ws_size,
                              hipStream_t stream) {
    const float* x   = (const float*)d_in[0];
    const float* Wqk = (const float*)d_in[1];
    const float* bqk = (const float*)d_in[2];
    const float* Wv  = (const float*)d_in[3];
    const float* bv  = (const float*)d_in[4];
    float* out = (float*)d_out;

    char* ws = (char*)d_ws;
    const size_t SZ_XB  = (size_t)MROWS*KDIM*2;   // 8 MB
    const size_t SZ_WT  = (size_t)NTOT*KDIM*2;    // 6 MB
    const size_t SZ_QKV = (size_t)MROWS*NTOT*2;   // 24 MB
    const size_t SZ_VT  = (size_t)32*64*SEQ*2;    // 8 MB
    __bf16* xb    = (__bf16*)(ws);
    __bf16* Wt    = (__bf16*)(ws + SZ_XB);
    __bf16* qkv   = (__bf16*)(ws + SZ_XB + SZ_WT);
    __bf16* vT    = (__bf16*)(ws + SZ_XB + SZ_WT + SZ_QKV);
    float*  biasc = (float* )(ws + SZ_XB + SZ_WT + SZ_QKV + SZ_VT);

    cast_x_kernel     <<<4096, 256, 0, stream>>>(x, xb);
    transpose_w_kernel<<<dim3(48, 16), 256, 0, stream>>>(Wqk, Wv, Wt);
    build_bias_kernel <<<12, 256, 0, stream>>>(bqk, bv, biasc);
    gemm_qkv_kernel   <<<dim3(NTOT/BN, MROWS/BM), 256, 0, stream>>>(xb, Wt, biasc, qkv);
    transpose_v_kernel<<<dim3(32, 32), 256, 0, stream>>>(qkv, vT);
    attn_kernel       <<<dim3(32, 32), 256, 0, stream>>>(qkv, vT, out);
}